// Round 1
// baseline (819.647 us; speedup 1.0000x reference)
//
#include <hip/hip_runtime.h>

// Batched Hungarian matcher (Jonker-Volgenant shortest augmenting path),
// replicating the numpy reference bit-for-bit in float64 given identical
// f32 cost values.
//
// Problem: B=32, N=4096 predictions, M=128 targets.
// Reference transposes cost [N,M] -> Cm [M=128 rows, N=4096 cols], runs JV,
// outputs (batch, src=sorted prediction idx, tgt=target idx) int32, concat.

#define Bb 32
#define Nn 4096
#define Mm 128
#define Tt 512
#define Kk (Nn / Tt)   // 8 columns per thread
#define NW (Tt / 64)   // 8 waves

__global__ __launch_bounds__(Tt, 1)
void hungarian_kernel(const float* __restrict__ predict_scores,
                      const float* __restrict__ predict_points,
                      const int*   __restrict__ scores,
                      const float* __restrict__ points,
                      int* __restrict__ out)
{
    __shared__ double sh[Nn];          // shortest path cost per column
    __shared__ double vv[Nn];          // column duals
    __shared__ short  pathc[Nn];       // predecessor row per column
    __shared__ short  row4col[Nn];     // matched row per column (-1 = free)
    __shared__ unsigned char SCc[Nn];  // scanned-column flags
    __shared__ double uu[Mm];          // row duals
    __shared__ short  col4row[Mm];     // matched column per row (-1 = free)
    __shared__ unsigned char SRr[Mm];  // scanned-row flags
    __shared__ float  tx0[Mm], tx1[Mm];
    __shared__ int    tch[Mm];
    __shared__ double wmin[NW];
    __shared__ int    wjmin[NW];
    __shared__ double bc_minval;
    __shared__ int    bc_i;
    __shared__ int    bc_sink;

    const int b   = blockIdx.x;
    const int tid = threadIdx.x;

    // ---- load per-column (prediction) data into registers ----
    float negp0[Kk], negp1[Kk], qx0[Kk], qx1[Kk];
    const float* ps = predict_scores + (size_t)b * Nn * 2;
    const float* pp = predict_points + (size_t)b * Nn * 2;
    #pragma unroll
    for (int k = 0; k < Kk; ++k) {
        int j = tid + k * Tt;
        float s0 = ps[2 * j], s1 = ps[2 * j + 1];
        float mx = fmaxf(s0, s1);
        float e0 = expf(s0 - mx), e1 = expf(s1 - mx);
        float sm = e0 + e1;
        negp0[k] = -(e0 / sm);
        negp1[k] = -(e1 / sm);
        qx0[k] = pp[2 * j];
        qx1[k] = pp[2 * j + 1];
        vv[j] = 0.0;
        row4col[j] = -1;
    }
    if (tid < Mm) {
        uu[tid] = 0.0;
        col4row[tid] = -1;
        tx0[tid] = points[(size_t)b * Mm * 2 + 2 * tid];
        tx1[tid] = points[(size_t)b * Mm * 2 + 2 * tid + 1];
        tch[tid] = scores[(size_t)b * Mm + tid];
    }
    __syncthreads();

    // ---- JV outer loop over rows (targets) ----
    for (int cur_row = 0; cur_row < Mm; ++cur_row) {
        #pragma unroll
        for (int k = 0; k < Kk; ++k) {
            int j = tid + k * Tt;
            sh[j] = __builtin_inf();
            SCc[j] = 0;
        }
        if (tid < Mm) SRr[tid] = 0;
        if (tid == 0) { bc_i = cur_row; bc_minval = 0.0; bc_sink = -1; }
        __syncthreads();

        // ---- Dijkstra-like augmenting path search ----
        for (int step = 0; step < Nn; ++step) {
            const int    i    = bc_i;
            const double minv = bc_minval;
            const int    snk  = bc_sink;
            if (snk >= 0) break;          // uniform: read post-barrier
            if (tid == 0) SRr[i] = 1;

            const double ui = uu[i];
            const float  t0 = tx0[i], t1 = tx1[i];
            const int    ch = tch[i];

            double bv = __builtin_inf();
            int    bj = 0;
            #pragma unroll
            for (int k = 0; k < Kk; ++k) {
                int j = tid + k * Tt;
                double sj;
                if (SCc[j]) {
                    sj = __builtin_inf();
                } else {
                    // f32 cost exactly as reference: presence + (|dx|+|dy|)
                    float pres = (ch == 1) ? negp1[k] : negp0[k];
                    float l1   = fabsf(qx0[k] - t0) + fabsf(qx1[k] - t1);
                    float cf   = pres + l1;
                    // f64 reduced cost, same op order as numpy:
                    double r = ((minv + (double)cf) - ui) - vv[j];
                    sj = sh[j];
                    if (r < sj) { sj = r; sh[j] = r; pathc[j] = (short)i; }
                }
                // k ascending => j ascending; strict < keeps lowest j on tie
                if (sj < bv) { bv = sj; bj = j; }
            }
            // wave reduction (min, tie -> lowest column index, numpy argmin)
            #pragma unroll
            for (int off = 32; off > 0; off >>= 1) {
                double ov = __shfl_down(bv, off);
                int    oj = __shfl_down(bj, off);
                if (ov < bv || (ov == bv && oj < bj)) { bv = ov; bj = oj; }
            }
            if ((tid & 63) == 0) { wmin[tid >> 6] = bv; wjmin[tid >> 6] = bj; }
            __syncthreads();
            if (tid == 0) {
                double best = wmin[0]; int bestj = wjmin[0];
                #pragma unroll
                for (int w = 1; w < NW; ++w) {
                    double ov = wmin[w]; int oj = wjmin[w];
                    if (ov < best || (ov == best && oj < bestj)) { best = ov; bestj = oj; }
                }
                bc_minval = best;
                SCc[bestj] = 1;
                int r = row4col[bestj];
                if (r < 0) bc_sink = bestj; else bc_i = r;
            }
            __syncthreads();
        }

        // ---- dual update (before augmentation, as in reference) ----
        const double minv = bc_minval;   // == shortest[sink]
        if (tid < Mm) {
            if (tid == cur_row) {
                uu[tid] += minv;
            } else if (SRr[tid]) {
                uu[tid] += minv - sh[col4row[tid]];
            }
        }
        #pragma unroll
        for (int k = 0; k < Kk; ++k) {
            int j = tid + k * Tt;
            if (SCc[j]) vv[j] -= minv - sh[j];
        }
        __syncthreads();

        // ---- augment along alternating path (sequential, short) ----
        if (tid == 0) {
            int j = bc_sink;
            for (;;) {
                int i2 = pathc[j];
                row4col[j] = (short)i2;
                int nxt = col4row[i2];
                col4row[i2] = (short)j;
                j = nxt;
                if (i2 == cur_row) break;
            }
        }
        __syncthreads();
    }

    // ---- emit (batch, src sorted ascending, tgt) ----
    if (tid < Mm) {
        int myj = col4row[tid];
        int rank = 0;
        #pragma unroll 4
        for (int t = 0; t < Mm; ++t) rank += (col4row[t] < myj) ? 1 : 0;
        out[b * Mm + tid] = b;                            // batch_idx
        out[Bb * Mm + b * Mm + rank] = myj;               // src_idx (sorted)
        out[2 * Bb * Mm + b * Mm + rank] = tid;           // tgt_idx
    }
}

extern "C" void kernel_launch(void* const* d_in, const int* in_sizes, int n_in,
                              void* d_out, int out_size, void* d_ws, size_t ws_size,
                              hipStream_t stream) {
    (void)in_sizes; (void)n_in; (void)d_ws; (void)ws_size; (void)out_size;
    const float* predict_scores = (const float*)d_in[0];
    const float* predict_points = (const float*)d_in[1];
    const int*   scores         = (const int*)d_in[2];
    const float* points         = (const float*)d_in[3];
    int* out = (int*)d_out;
    hipLaunchKernelGGL(hungarian_kernel, dim3(Bb), dim3(Tt), 0, stream,
                       predict_scores, predict_points, scores, points, out);
}

// Round 2
// 666.071 us; speedup vs baseline: 1.2306x; 1.2306x over previous
//
#include <hip/hip_runtime.h>

// Batched Hungarian matcher (Jonker-Volgenant shortest augmenting path),
// bit-exact vs the numpy reference in float64 given identical f32 costs.
//
// B=32 blocks, one per batch. 512 threads; each thread owns 8 of the 4096
// columns (j = tid + k*512). Register-resident per-column state:
//   shortest (f64 x8), scanned-flag (bitmask), per-col cost inputs.
// LDS holds only: v duals (read-only in hot loop), path predecessors
// (write-only in hot loop), matching arrays, and O(S) dual-update records.
// One __syncthreads() per Dijkstra step (parity-double-buffered reduction).

#define Bb 32
#define Nn 4096
#define Mm 128
#define Tt 512
#define Kk (Nn / Tt)   // 8 columns per thread
#define TSH 9          // log2(Tt)
#define NW (Tt / 64)   // 8 waves

__global__ __launch_bounds__(Tt, 1)
void hungarian_kernel(const float* __restrict__ predict_scores,
                      const float* __restrict__ predict_points,
                      const int*   __restrict__ scores,
                      const float* __restrict__ points,
                      int* __restrict__ out)
{
    __shared__ double vvl[Nn];          // column duals (read in hot loop)
    __shared__ short  path_lds[Nn];     // predecessor row (write-only in hot loop)
    __shared__ short  row4col[Nn];      // matched row per column (-1 = free)
    __shared__ double uu[Mm];           // row duals
    __shared__ short  col4row[Mm];      // matched column per row (-1 = free)
    __shared__ double srow_val[Mm];     // minval when row was scanned
    __shared__ unsigned char SRr[Mm];   // scanned-row flags
    __shared__ float  tx0[Mm], tx1[Mm];
    __shared__ int    tch[Mm];
    __shared__ int    scol[Mm + 8];     // scanned (matched) columns this row
    __shared__ double sval[Mm + 8];     // shortest value at their scan step
    __shared__ int    nsc_lds;
    __shared__ double wminb[2][NW];     // parity-double-buffered reduction
    __shared__ int    wjminb[2][NW];

    const int b   = blockIdx.x;
    const int tid = threadIdx.x;
    const double INFD = __builtin_inf();

    // ---- per-column (prediction) data -> registers ----
    float negp0[Kk], negp1[Kk], qx0[Kk], qx1[Kk];
    const float* ps = predict_scores + (size_t)b * Nn * 2;
    const float* pp = predict_points + (size_t)b * Nn * 2;
    #pragma unroll
    for (int k = 0; k < Kk; ++k) {
        int j = tid + (k << TSH);
        float s0 = ps[2 * j], s1 = ps[2 * j + 1];
        float mx = fmaxf(s0, s1);
        float e0 = expf(s0 - mx), e1 = expf(s1 - mx);
        float sm = e0 + e1;
        negp0[k] = -(e0 / sm);
        negp1[k] = -(e1 / sm);
        qx0[k] = pp[2 * j];
        qx1[k] = pp[2 * j + 1];
        vvl[j] = 0.0;
        row4col[j] = -1;
    }
    if (tid < Mm) {
        uu[tid] = 0.0;
        col4row[tid] = -1;
        SRr[tid] = 0;
        tx0[tid] = points[(size_t)b * Mm * 2 + 2 * tid];
        tx1[tid] = points[(size_t)b * Mm * 2 + 2 * tid + 1];
        tch[tid] = scores[(size_t)b * Mm + tid];
    }
    __syncthreads();

    // ---- JV outer loop over rows (targets) ----
    for (int cur_row = 0; cur_row < Mm; ++cur_row) {
        double shr[Kk];
        #pragma unroll
        for (int k = 0; k < Kk; ++k) shr[k] = INFD;
        unsigned scmask = 0;      // per-thread scanned-column bits
        int    i    = cur_row;    // all uniform across the block
        double minv = 0.0;
        int    sink = -1;
        int    p    = 0;
        int    nsc  = 0;          // tid0-only list length

        for (;;) {
            // ---- scan all unscanned columns for current row i ----
            const double ui = uu[i];
            const float  t0 = tx0[i], t1 = tx1[i];
            const int    ch = tch[i];
            double bv = INFD;
            int    bj = 0;
            #pragma unroll
            for (int k = 0; k < Kk; ++k) {
                int j = tid + (k << TSH);
                float pres = (ch == 1) ? negp1[k] : negp0[k];
                float l1   = fabsf(qx0[k] - t0) + fabsf(qx1[k] - t1);
                float cf   = pres + l1;                       // f32 cost, as ref
                double r = ((minv + (double)cf) - ui) - vvl[j]; // f64, ref order
                bool sc = (scmask >> k) & 1u;
                if (!sc && r < shr[k]) { shr[k] = r; path_lds[j] = (short)i; }
                double sj = sc ? INFD : shr[k];
                if (sj < bv) { bv = sj; bj = j; }  // k asc => lowest j on tie
            }
            // ---- wave argmin (tie -> lowest column index) ----
            #pragma unroll
            for (int off = 32; off > 0; off >>= 1) {
                double ov = __shfl_down(bv, off);
                int    oj = __shfl_down(bj, off);
                if (ov < bv || (ov == bv && oj < bj)) { bv = ov; bj = oj; }
            }
            if ((tid & 63) == 0) { wminb[p][tid >> 6] = bv; wjminb[p][tid >> 6] = bj; }
            __syncthreads();
            // ---- every thread computes the uniform global argmin ----
            double best = wminb[p][0]; int bestj = wjminb[p][0];
            #pragma unroll
            for (int w = 1; w < NW; ++w) {
                double ov = wminb[p][w]; int oj = wjminb[p][w];
                if (ov < best || (ov == best && oj < bestj)) { best = ov; bestj = oj; }
            }
            p ^= 1;
            minv = best;
            if ((bestj & (Tt - 1)) == tid) scmask |= (1u << (bestj >> TSH));
            int r4 = row4col[bestj];
            if (r4 < 0) {
                if (tid == 0) nsc_lds = nsc;
                sink = bestj;
                break;                       // uniform exit
            }
            if (tid == 0) {                  // O(S) dual-update bookkeeping
                SRr[r4] = 1;
                srow_val[r4] = best;         // == shortest[col4row[r4]]
                scol[nsc] = bestj; sval[nsc] = best; ++nsc;
            }
            i = r4;
        }
        __syncthreads();

        const double minvf = minv;           // == shortest[sink]
        // ---- dual updates (O(M) + O(S), bit-equal to reference) ----
        if (tid < Mm) {
            if (tid == cur_row)   uu[tid] += minvf;
            else if (SRr[tid])    uu[tid] += minvf - srow_val[tid];
            SRr[tid] = 0;                    // clear for next row
        }
        int S = nsc_lds;
        if (tid < S) {
            int jc = scol[tid];
            vvl[jc] -= (minvf - sval[tid]);  // sink entry would be exactly 0
        }
        // ---- augment along alternating path (tid0, concurrent w/ above) ----
        if (tid == 0) {
            int j = sink;
            for (;;) {
                int i2 = path_lds[j];
                row4col[j] = (short)i2;
                int nxt = col4row[i2];
                col4row[i2] = (short)j;
                j = nxt;
                if (i2 == cur_row) break;
            }
        }
        __syncthreads();
    }

    // ---- emit (batch, src sorted ascending, tgt) ----
    if (tid < Mm) {
        int myj = col4row[tid];
        int rank = 0;
        #pragma unroll 4
        for (int t = 0; t < Mm; ++t) rank += (col4row[t] < myj) ? 1 : 0;
        out[b * Mm + tid] = b;                  // batch_idx
        out[Bb * Mm + b * Mm + rank] = myj;     // src_idx (sorted)
        out[2 * Bb * Mm + b * Mm + rank] = tid; // tgt_idx
    }
}

extern "C" void kernel_launch(void* const* d_in, const int* in_sizes, int n_in,
                              void* d_out, int out_size, void* d_ws, size_t ws_size,
                              hipStream_t stream) {
    (void)in_sizes; (void)n_in; (void)d_ws; (void)ws_size; (void)out_size;
    const float* predict_scores = (const float*)d_in[0];
    const float* predict_points = (const float*)d_in[1];
    const int*   scores         = (const int*)d_in[2];
    const float* points         = (const float*)d_in[3];
    int* out = (int*)d_out;
    hipLaunchKernelGGL(hungarian_kernel, dim3(Bb), dim3(Tt), 0, stream,
                       predict_scores, predict_points, scores, points, out);
}

// Round 3
// 635.589 us; speedup vs baseline: 1.2896x; 1.0480x over previous
//
#include <hip/hip_runtime.h>

// Batched Hungarian matcher (Jonker-Volgenant shortest augmenting path),
// bit-exact vs the numpy reference given identical f32 costs.
//
// R3: pruned-candidate search. Per row i, an EXACT candidate set
// C_i = { j : cf(i,j) < theta_i } (|C_i| <= 64) is precomputed. During the
// shortest-augmenting-path search only candidate columns are updated; a
// rigorous lower bound LB = min_s ((minv_s + theta_{i_s}) - u_{i_s}) over
// scanned rows bounds every omitted update (v[j] <= 0, fp-add monotone).
// Each pop is accepted only if best < LB => pop identical to numpy's.
// Otherwise the row is undone and re-run with the proven full-scan path.
// Search runs on wave 0 only: zero barriers per pop (wave lockstep + DS
// in-order semantics), butterfly argmin, compact slot list for 'shortest'.

#define Bb 32
#define Nn 4096
#define Mm 128
#define Tt 512
#define Kk (Nn / Tt)   // 8 columns per thread (full-scan fallback)
#define TSH 9          // log2(Tt)
#define NW (Tt / 64)   // 8 waves
#define CAP 64         // max candidates per row
#define TLCAP 1024     // max touched slots per row-search
#define POPCAP 132
#define NTH 6          // thresholds tried per row

__global__ __launch_bounds__(Tt, 1)
void hungarian_kernel(const float* __restrict__ predict_scores,
                      const float* __restrict__ predict_points,
                      const int*   __restrict__ scores,
                      const float* __restrict__ points,
                      int* __restrict__ out)
{
    // ---- LDS (~157 KB; gfx950 allows 160 KiB/WG) ----
    __shared__ double vvl[Nn];            // column duals (-inf = popped this row)
    __shared__ unsigned short pos[Nn];    // col -> slot (0xFFFF = untouched)
    __shared__ double shc[TLCAP];         // compact 'shortest' per slot
    __shared__ unsigned short tlj[TLCAP]; // slot -> col
    __shared__ float pn0[Nn], pn1[Nn];    // -softmax probs (f32, exact)
    __shared__ float qx0l[Nn], qx1l[Nn];  // prediction points
    __shared__ unsigned short cidx[Mm * CAP];
    __shared__ int    ccnt[Mm];
    __shared__ float  theta[Mm];
    __shared__ short  path_lds[Nn];
    __shared__ short  row4col[Nn];
    __shared__ double uu[Mm];
    __shared__ short  col4row[Mm];
    __shared__ double srow_val[Mm];
    __shared__ unsigned char SRr[Mm];
    __shared__ float  tx0[Mm], tx1[Mm];
    __shared__ int    tch[Mm];
    __shared__ int    pop_j[POPCAP];
    __shared__ double pop_minv[POPCAP];
    __shared__ double pop_vold[POPCAP];
    __shared__ double wminb[2][NW];       // full-scan reduction (parity)
    __shared__ int    wjminb[2][NW];
    __shared__ int    fbflag, Llds, Slds, sink_lds;
    __shared__ double minv_lds;

    const int b   = blockIdx.x;
    const int tid = threadIdx.x;
    const double INFD = __builtin_inf();

    // ---- per-column data -> registers (fallback) + LDS (pruned path) ----
    float negp0[Kk], negp1[Kk], qx0[Kk], qx1[Kk];
    const float* ps = predict_scores + (size_t)b * Nn * 2;
    const float* pp = predict_points + (size_t)b * Nn * 2;
    #pragma unroll
    for (int k = 0; k < Kk; ++k) {
        int j = tid + (k << TSH);
        float s0 = ps[2 * j], s1 = ps[2 * j + 1];
        float mx = fmaxf(s0, s1);
        float e0 = expf(s0 - mx), e1 = expf(s1 - mx);
        float sm = e0 + e1;
        negp0[k] = -(e0 / sm);
        negp1[k] = -(e1 / sm);
        qx0[k] = pp[2 * j];
        qx1[k] = pp[2 * j + 1];
        pn0[j] = negp0[k];  pn1[j] = negp1[k];
        qx0l[j] = qx0[k];   qx1l[j] = qx1[k];
        vvl[j] = 0.0;
        row4col[j] = -1;
        pos[j] = 0xFFFF;
    }
    if (tid < Mm) {
        uu[tid] = 0.0;
        col4row[tid] = -1;
        SRr[tid] = 0;
        ccnt[tid] = 0;
        tx0[tid] = points[(size_t)b * Mm * 2 + 2 * tid];
        tx1[tid] = points[(size_t)b * Mm * 2 + 2 * tid + 1];
        tch[tid] = scores[(size_t)b * Mm + tid];
    }
    __syncthreads();

    // ---- candidate selection: wave w handles rows w*16..w*16+15 ----
    {
        const int wv = tid >> 6, lane = tid & 63;
        for (int rr = 0; rr < Mm / NW; ++rr) {
            int i = wv * (Mm / NW) + rr;
            float t0 = tx0[i], t1 = tx1[i];
            const float* pn = (tch[i] == 1) ? pn1 : pn0;
            // pass 1: row min
            float m = __builtin_inff();
            for (int t = 0; t < Nn / 64; ++t) {
                int j = lane + (t << 6);
                float cf = pn[j] + fabsf(qx0l[j] - t0) + fabsf(qx1l[j] - t1);
                m = fminf(m, cf);
            }
            #pragma unroll
            for (int off = 32; off > 0; off >>= 1)
                m = fminf(m, __shfl_xor(m, off));
            // pass 2: count for NTH thresholds
            float th[NTH] = {m + 0.64f, m + 0.16f, m + 0.04f,
                             m + 0.01f, m + 0.0025f, m + 0.000625f};
            int cnt[NTH];
            #pragma unroll
            for (int q = 0; q < NTH; ++q) cnt[q] = 0;
            for (int t = 0; t < Nn / 64; ++t) {
                int j = lane + (t << 6);
                float cf = pn[j] + fabsf(qx0l[j] - t0) + fabsf(qx1l[j] - t1);
                #pragma unroll
                for (int q = 0; q < NTH; ++q) cnt[q] += (cf < th[q]) ? 1 : 0;
            }
            #pragma unroll
            for (int q = 0; q < NTH; ++q) {
                #pragma unroll
                for (int off = 32; off > 0; off >>= 1)
                    cnt[q] += __shfl_xor(cnt[q], off);
            }
            // pick largest theta with cnt <= CAP (cnt monotone in theta)
            float chosen = -__builtin_inff();
            int have = 0;
            #pragma unroll
            for (int q = 0; q < NTH; ++q)
                if (!have && cnt[q] <= CAP) { chosen = th[q]; have = 1; }
            if (lane == 0) theta[i] = chosen;
            if (have) {
                for (int t = 0; t < Nn / 64; ++t) {
                    int j = lane + (t << 6);
                    float cf = pn[j] + fabsf(qx0l[j] - t0) + fabsf(qx1l[j] - t1);
                    if (cf < chosen) {
                        int slot = atomicAdd(&ccnt[i], 1);
                        cidx[i * CAP + slot] = (unsigned short)j;
                    }
                }
            }
        }
    }
    __syncthreads();

    // ---- JV outer loop over rows (targets) ----
    for (int cur_row = 0; cur_row < Mm; ++cur_row) {
        if (tid == 0) fbflag = 0;
        __syncthreads();

        // ========== pruned search: wave 0 only, no barriers ==========
        if (tid < 64) {
            const int lane = tid;
            int L = 0, S = 0;
            double LB = INFD, minv = 0.0;
            int i = cur_row, sink = -1, fb = 0;
            for (int iter = 0; iter < 200; ++iter) {
                const double th = (double)theta[i];
                const double ui = uu[i];
                const float  t0 = tx0[i], t1 = tx1[i];
                const int    ch = tch[i];
                const int    cc = ccnt[i];
                double lbterm = (minv + th) - ui;
                LB = fmin(LB, lbterm);
                // --- A: candidate updates (1 per lane) ---
                double av = INFD; int aj = Nn;
                int Lold = L;
                bool allocate = false; int jA = 0; double rA = 0.0;
                if (lane < cc) {
                    int j = cidx[i * CAP + lane];
                    float pres = (ch == 1) ? pn1[j] : pn0[j];
                    float cf = pres + fabsf(qx0l[j] - t0) + fabsf(qx1l[j] - t1);
                    double r = ((minv + (double)cf) - ui) - vvl[j]; // +inf if popped
                    unsigned short p = pos[j];
                    if (p == 0xFFFF) {           // first touch (never popped)
                        allocate = true; jA = j; rA = r;
                        av = r; aj = j;
                    } else {
                        double old = shc[p];
                        if (r < old) { shc[p] = r; path_lds[j] = (short)i; av = r; }
                        else av = old;
                        aj = j;
                    }
                }
                unsigned long long amask = __ballot(allocate);
                int nalloc = (int)__popcll(amask);
                if (Lold + nalloc > TLCAP) { fb = 1; break; }
                if (allocate) {
                    int slot = Lold + (int)__popcll(amask & ((1ull << lane) - 1ull));
                    shc[slot] = rA;
                    tlj[slot] = (unsigned short)jA;
                    pos[jA] = (unsigned short)slot;
                    path_lds[jA] = (short)i;
                }
                L = Lold + nalloc;
                // --- B: linear slot scan ---
                double bv = av; int bj = aj;
                for (int s = lane; s < Lold; s += 64) {
                    double v = shc[s]; int jj = tlj[s];
                    if (v < bv || (v == bv && jj < bj)) { bv = v; bj = jj; }
                }
                // --- butterfly argmin (all lanes get result) ---
                #pragma unroll
                for (int off = 32; off > 0; off >>= 1) {
                    double ov = __shfl_xor(bv, off);
                    int    oj = __shfl_xor(bj, off);
                    if (ov < bv || (ov == bv && oj < bj)) { bv = ov; bj = oj; }
                }
                if (!(bv < LB)) { fb = 1; break; }   // exactness gate
                minv = bv;
                int bestj = bj;
                int r4 = row4col[bestj];
                unsigned short psl = pos[bestj];
                if (lane == 0) {
                    pop_j[S] = bestj; pop_minv[S] = minv; pop_vold[S] = vvl[bestj];
                    vvl[bestj] = -INFD;      // poison: no revive
                    shc[psl]   = INFD;       // poison: no re-pop
                }
                S++;
                if (r4 < 0) { sink = bestj; break; }
                if (lane == 1) { SRr[r4] = 1; srow_val[r4] = minv; }
                i = r4;
            }
            if (sink < 0 && !fb) fb = 1;  // safety
            if (fb) {
                // undo everything this row touched
                for (int s = lane; s < L; s += 64) pos[tlj[s]] = 0xFFFF;
                for (int e = lane; e < S; e += 64) {
                    int j = pop_j[e];
                    vvl[j] = pop_vold[e];
                    int r4 = row4col[j];
                    if (r4 >= 0) SRr[r4] = 0;
                }
                if (lane == 0) fbflag = 1;
            } else if (lane == 0) {
                Llds = L; Slds = S; sink_lds = sink; minv_lds = minv;
            }
        }
        __syncthreads();

        if (fbflag) {
            // ========== full-scan fallback (proven R2 path, all 512) ==========
            double shr[Kk];
            #pragma unroll
            for (int k = 0; k < Kk; ++k) shr[k] = INFD;
            unsigned scmask = 0;
            int fi = cur_row; double fminv = 0.0; int fsink = -1;
            int par = 0, nsc = 0;
            for (;;) {
                const double ui = uu[fi];
                const float t0 = tx0[fi], t1 = tx1[fi];
                const int ch = tch[fi];
                double bv = INFD; int bj = 0;
                #pragma unroll
                for (int k = 0; k < Kk; ++k) {
                    int j = tid + (k << TSH);
                    float pres = (ch == 1) ? negp1[k] : negp0[k];
                    float l1 = fabsf(qx0[k] - t0) + fabsf(qx1[k] - t1);
                    float cf = pres + l1;
                    double r = ((fminv + (double)cf) - ui) - vvl[j];
                    bool sc = (scmask >> k) & 1u;
                    if (!sc && r < shr[k]) { shr[k] = r; path_lds[j] = (short)fi; }
                    double sj = sc ? INFD : shr[k];
                    if (sj < bv) { bv = sj; bj = j; }
                }
                #pragma unroll
                for (int off = 32; off > 0; off >>= 1) {
                    double ov = __shfl_down(bv, off);
                    int    oj = __shfl_down(bj, off);
                    if (ov < bv || (ov == bv && oj < bj)) { bv = ov; bj = oj; }
                }
                if ((tid & 63) == 0) { wminb[par][tid >> 6] = bv; wjminb[par][tid >> 6] = bj; }
                __syncthreads();
                double best = wminb[par][0]; int bestj = wjminb[par][0];
                #pragma unroll
                for (int w = 1; w < NW; ++w) {
                    double ov = wminb[par][w]; int oj = wjminb[par][w];
                    if (ov < best || (ov == best && oj < bestj)) { best = ov; bestj = oj; }
                }
                par ^= 1;
                fminv = best;
                if ((bestj & (Tt - 1)) == tid) scmask |= (1u << (bestj >> TSH));
                int r4 = row4col[bestj];
                if (r4 < 0) {
                    if (tid == 0) Slds = nsc;
                    fsink = bestj;
                    break;
                }
                if (tid == 0) {
                    SRr[r4] = 1; srow_val[r4] = best;
                    pop_j[nsc] = bestj; pop_minv[nsc] = best; ++nsc;
                }
                fi = r4;
            }
            __syncthreads();
            const double minvf = fminv;
            if (tid < Mm) {
                if (tid == cur_row)   uu[tid] += minvf;
                else if (SRr[tid])    uu[tid] += minvf - srow_val[tid];
                SRr[tid] = 0;
            }
            int S2 = Slds;
            if (tid < S2) {
                int jc = pop_j[tid];
                vvl[jc] -= (minvf - pop_minv[tid]);
            }
            if (tid == 0) {
                int j = fsink;
                for (;;) {
                    int i2 = path_lds[j];
                    row4col[j] = (short)i2;
                    int nxt = col4row[i2];
                    col4row[i2] = (short)j;
                    j = nxt;
                    if (i2 == cur_row) break;
                }
            }
        } else {
            // ========== pruned row-end (all 512) ==========
            const double minvf = minv_lds;
            const int S = Slds, L = Llds;
            if (tid < Mm) {
                if (tid == cur_row)   uu[tid] += minvf;
                else if (SRr[tid])    uu[tid] += minvf - srow_val[tid];
                SRr[tid] = 0;
            }
            for (int e = tid; e < S; e += Tt) {
                // includes sink: vold - (minvf - minvf) = vold (un-poisons)
                vvl[pop_j[e]] = pop_vold[e] - (minvf - pop_minv[e]);
            }
            for (int s = tid; s < L; s += Tt) pos[tlj[s]] = 0xFFFF;
            if (tid == 0) {
                int j = sink_lds;
                for (;;) {
                    int i2 = path_lds[j];
                    row4col[j] = (short)i2;
                    int nxt = col4row[i2];
                    col4row[i2] = (short)j;
                    j = nxt;
                    if (i2 == cur_row) break;
                }
            }
        }
    }
    __syncthreads();

    // ---- emit (batch, src sorted ascending, tgt) ----
    if (tid < Mm) {
        int myj = col4row[tid];
        int rank = 0;
        #pragma unroll 4
        for (int t = 0; t < Mm; ++t) rank += (col4row[t] < myj) ? 1 : 0;
        out[b * Mm + tid] = b;                  // batch_idx
        out[Bb * Mm + b * Mm + rank] = myj;     // src_idx (sorted)
        out[2 * Bb * Mm + b * Mm + rank] = tid; // tgt_idx
    }
}

extern "C" void kernel_launch(void* const* d_in, const int* in_sizes, int n_in,
                              void* d_out, int out_size, void* d_ws, size_t ws_size,
                              hipStream_t stream) {
    (void)in_sizes; (void)n_in; (void)d_ws; (void)ws_size; (void)out_size;
    const float* predict_scores = (const float*)d_in[0];
    const float* predict_points = (const float*)d_in[1];
    const int*   scores         = (const int*)d_in[2];
    const float* points         = (const float*)d_in[3];
    int* out = (int*)d_out;
    hipLaunchKernelGGL(hungarian_kernel, dim3(Bb), dim3(Tt), 0, stream,
                       predict_scores, predict_points, scores, points, out);
}